// Round 6
// baseline (109.640 us; speedup 1.0000x reference)
//
#include <hip/hip_runtime.h>

typedef float vf4 __attribute__((ext_vector_type(4)));
typedef float vf2 __attribute__((ext_vector_type(2)));

#define LOG2E 1.4426950408889634f
#define TWO_LOG2E 2.8853900817779268f

__device__ __forceinline__ float fexp2(float x) { return __builtin_amdgcn_exp2f(x); }
__device__ __forceinline__ float frcp(float x) { return __builtin_amdgcn_rcpf(x); }

// ---------------------------------------------------------------------------
// Kernel 1 v3: projections, k-split x4, exp folded into the epilogue (stores
// Ep = exp2(2*log2e * acc_quarter); scores multiplies the 4 quarter-exps).
// Geometry: tile 128m x 64n, 256 threads, 8m x 4n micro-tile (m covered as
// {tm4..tm4+3} and {tm4+64..tm4+67}), grid (32,4,4)=512 = 2 blocks/CU =
// 8 waves/CU (2/SIMD — R4 lesson: never drop below 2 waves/SIMD).
// LDS cost: 3 b128 per 32 FMA = 1.5 B/FMA (was 2.0).  Bank checks:
//  - A-read at (t&15)*4 / +64: 16 addrs x 4-lane broadcast, 2-way = free.
//  - A-stage: row delta 8*132 == 0 mod 32 -> 2-way free.
//  - B-stage: row delta 4*68 == 16 mod 32 -> 2-way free.
// Block (0,0,0) also zeroes Rsum[2048].
__global__ __launch_bounds__(256) void proj_kernel(
    const float* __restrict__ queries, const float* __restrict__ keyes,
    const float* __restrict__ Wq, const float* __restrict__ Wk,
    float* __restrict__ QpH, float* __restrict__ KpH,
    float* __restrict__ Rsum) {
  __shared__ alignas(16) float At[16 * 132];  // [k][m], 128 m + pad
  __shared__ alignas(16) float Bt[16 * 68];   // [k][n], 64 n + pad
  const int t = threadIdx.x;
  if (blockIdx.x == 0 && blockIdx.y == 0 && blockIdx.z == 0) {
    *(vf4*)&Rsum[t * 8] = (vf4){0.f, 0.f, 0.f, 0.f};
    *(vf4*)&Rsum[t * 8 + 4] = (vf4){0.f, 0.f, 0.f, 0.f};
  }
  const int m0 = blockIdx.x * 128;
  const int n0 = blockIdx.y * 64;
  const int k0 = blockIdx.z * 64;  // k-quarter
  const bool isQ = (m0 < 2048);
  const float* X = isQ ? queries : keyes;
  const float* W = isQ ? Wq : Wk;
  float* C = (isQ ? QpH : KpH) + blockIdx.z * 524288;
  const int mb = isQ ? m0 : (m0 - 2048);

  const int lmA = t >> 1;  // A staging: row 0..127
  const int lqA = t & 1;   // k-octet
  const int lmB = t >> 2;  // B staging: row 0..63
  const int lqB = t & 3;   // k-quad
  const int tm4 = (t & 15) * 4;
  const int tn4 = (t >> 4) * 4;

  float acc[8][4] = {};
  for (int kc = k0; kc < k0 + 64; kc += 16) {
    __syncthreads();
    const float* asrc = &X[(mb + lmA) * 256 + kc + lqA * 8];
    vf4 xa0 = *(const vf4*)asrc;
    vf4 xa1 = *(const vf4*)(asrc + 4);
    vf4 wb = *(const vf4*)&W[(n0 + lmB) * 256 + kc + lqB * 4];
#pragma unroll
    for (int c = 0; c < 4; ++c) {
      At[(lqA * 8 + c) * 132 + lmA] = xa0[c];
      At[(lqA * 8 + 4 + c) * 132 + lmA] = xa1[c];
      Bt[(lqB * 4 + c) * 68 + lmB] = wb[c];
    }
    __syncthreads();
#pragma unroll
    for (int kk = 0; kk < 16; ++kk) {
      vf4 a0 = *(const vf4*)&At[kk * 132 + tm4];
      vf4 a1 = *(const vf4*)&At[kk * 132 + tm4 + 64];
      vf4 b4 = *(const vf4*)&Bt[kk * 68 + tn4];
#pragma unroll
      for (int i = 0; i < 4; ++i)
#pragma unroll
        for (int j = 0; j < 4; ++j) {
          acc[i][j] += a0[i] * b4[j];
          acc[4 + i][j] += a1[i] * b4[j];
        }
    }
  }
#pragma unroll
  for (int i = 0; i < 4; ++i) {
    vf4 o0 = {fexp2(acc[i][0] * TWO_LOG2E), fexp2(acc[i][1] * TWO_LOG2E),
              fexp2(acc[i][2] * TWO_LOG2E), fexp2(acc[i][3] * TWO_LOG2E)};
    *(vf4*)&C[(mb + tm4 + i) * 256 + n0 + tn4] = o0;
    vf4 o1 = {fexp2(acc[4 + i][0] * TWO_LOG2E), fexp2(acc[4 + i][1] * TWO_LOG2E),
              fexp2(acc[4 + i][2] * TWO_LOG2E), fexp2(acc[4 + i][3] * TWO_LOG2E)};
    *(vf4*)&C[(mb + 64 + tm4 + i) * 256 + n0 + tn4] = o1;
  }
}

// ---------------------------------------------------------------------------
// Kernel 2 (dominant): scores via precomputed exponentials.  Same structure
// as R3-proven version; staging now multiplies FOUR quarter-exps (k-split x4).
// Wv through scalar cache, 4-way rational rcp combining.
// score = Swv - 2*acc;  E[b][j][i] = masked ? 1 : exp(score); fused row sums
// via atomicAdd into Rsum. Tile 32i x 32j x h=256, grid 8x8x8 = 512.
__global__ __launch_bounds__(256) void scores_exp_kernel(
    const float* __restrict__ QpH, const float* __restrict__ KpH,
    const float* __restrict__ Wv, const int* __restrict__ valid_lens,
    float* __restrict__ E, float* __restrict__ Rsum) {
  __shared__ alignas(16) float Qs[32 * 32];
  __shared__ alignas(16) float Ks[32 * 32];
  const int t = threadIdx.x;
  const int i0 = blockIdx.x * 32;
  const int j0 = blockIdx.y * 32;
  const int b = blockIdx.z;
  const int ti = t & 15;   // i = i0 + ti (+16)
  const int tj = t >> 4;   // j = j0 + tj (+16)

  float Swv;  // sum_h wv[h]
  {
    vf4 w4 = *(const vf4*)&Wv[(t & 63) * 4];
    float sw = w4[0] + w4[1] + w4[2] + w4[3];
#pragma unroll
    for (int off = 1; off < 64; off <<= 1) sw += __shfl_xor(sw, off, 64);
    Swv = sw;
  }

  const int srow = t >> 3;       // staging row 0..31
  const int scg = t & 7;         // staging col-group 0..7
  const int swcol = ((scg ^ (srow & 7)) << 2);
  const int qxor = ti & 7;
  const int kxor = tj & 7;

  float acc[2][2] = {};
  for (int hc = 0; hc < 8; ++hc) {
    __syncthreads();
    const int qoff = (((b << 8) + i0 + srow) << 8) + hc * 32 + scg * 4;
    const int koff = (((b << 8) + j0 + srow) << 8) + hc * 32 + scg * 4;
    vf4 qv = *(const vf4*)&QpH[qoff] * *(const vf4*)&QpH[524288 + qoff] *
             *(const vf4*)&QpH[2 * 524288 + qoff] *
             *(const vf4*)&QpH[3 * 524288 + qoff];
    vf4 kv = *(const vf4*)&KpH[koff] * *(const vf4*)&KpH[524288 + koff] *
             *(const vf4*)&KpH[2 * 524288 + koff] *
             *(const vf4*)&KpH[3 * 524288 + koff];
    *(vf4*)&Qs[srow * 32 + swcol] = qv;  // product of quarter-exps
    *(vf4*)&Ks[srow * 32 + swcol] = kv;
    __syncthreads();
#pragma unroll
    for (int hh = 0; hh < 8; ++hh) {
      vf4 q0 = *(const vf4*)&Qs[ti * 32 + ((hh ^ qxor) << 2)];
      vf4 q1 = *(const vf4*)&Qs[(ti + 16) * 32 + ((hh ^ qxor) << 2)];
      vf4 k0 = *(const vf4*)&Ks[tj * 32 + ((hh ^ kxor) << 2)];
      vf4 k1 = *(const vf4*)&Ks[(tj + 16) * 32 + ((hh ^ kxor) << 2)];
      const int hb = hc * 32 + hh * 4;
      const float w0 = Wv[hb + 0];  // uniform -> scalar cache, not LDS
      const float w1 = Wv[hb + 1];
      const float w2 = Wv[hb + 2];
      const float w3 = Wv[hb + 3];
      // sum_e w_e / A_e with one rcp: (n01*d23 + n23*d01) / (d01*d23)
      auto term = [&](const vf4& q, const vf4& k, float& a) {
        float A0 = __builtin_fmaf(q[0], k[0], 1.0f);
        float A1 = __builtin_fmaf(q[1], k[1], 1.0f);
        float A2 = __builtin_fmaf(q[2], k[2], 1.0f);
        float A3 = __builtin_fmaf(q[3], k[3], 1.0f);
        float d01 = A0 * A1;
        float d23 = A2 * A3;
        float n01 = __builtin_fmaf(w0, A1, w1 * A0);
        float n23 = __builtin_fmaf(w2, A3, w3 * A2);
        float num = __builtin_fmaf(n01, d23, n23 * d01);
        a = __builtin_fmaf(num, frcp(d01 * d23), a);
      };
      term(q0, k0, acc[0][0]);
      term(q0, k1, acc[0][1]);
      term(q1, k0, acc[1][0]);
      term(q1, k1, acc[1][1]);
    }
  }

  const int len = valid_lens[b];
#pragma unroll
  for (int c = 0; c < 2; ++c) {
    const int j = j0 + tj + 16 * c;
    const bool masked = (j >= len);
    float ev[2];
#pragma unroll
    for (int r = 0; r < 2; ++r) {
      const int i = i0 + ti + 16 * r;
      const float score = Swv - 2.0f * acc[r][c];
      ev[r] = masked ? 1.0f : fexp2(score * LOG2E);
      E[(((b << 8) + j) << 8) + i] = ev[r];
    }
    float s = ev[0] + ev[1];
#pragma unroll
    for (int off = 1; off < 16; off <<= 1) s += __shfl_xor(s, off, 64);
    if (ti == 0) atomicAdd(&Rsum[(b << 8) + j], s);
  }
}

// ---------------------------------------------------------------------------
// Kernel 3: out[b,i,d] = sum_j (E[b,j,i]/Rsum[b,j]) * V[b,j,d].
// R5-proven v2: i micro-tile {2ti, 2ti+1} -> single b64 A-read per j.
// Tile 32i x 64d, 256 threads, grid 8x4x8 = 256 blocks.
__global__ __launch_bounds__(256) void out_kernel(
    const float* __restrict__ E, const float* __restrict__ Rsum,
    const float* __restrict__ V, float* __restrict__ out) {
  __shared__ alignas(16) float As[32 * 36];  // [j][i]
  __shared__ alignas(16) float Bs[32 * 68];  // [j][d]
  const int t = threadIdx.x;
  const int i0 = blockIdx.x * 32;
  const int d0 = blockIdx.y * 64;
  const int b = blockIdx.z;
  const int ti = t & 15;   // i-pair: rows 2ti, 2ti+1
  const int td = t >> 4;   // d = d0 + td*4
  const int sr = t >> 3;   // staging row 0..31
  const int sc4 = (t & 7) * 4;

  float acc[2][4] = {};
  for (int jc = 0; jc < 8; ++jc) {
    const int jb = jc * 32;
    __syncthreads();
    const float rj = frcp(Rsum[(b << 8) + jb + sr]);
    {
      vf4 a = *(const vf4*)&E[(((b << 8) + jb + sr) << 8) + i0 + sc4];
      *(vf4*)&As[sr * 36 + sc4] = a * rj;
    }
#pragma unroll
    for (int s = 0; s < 2; ++s) {
      const int col = sc4 + s * 32;
      *(vf4*)&Bs[sr * 68 + col] =
          *(const vf4*)&V[(((b << 8) + jb + sr) << 8) + d0 + col];
    }
    __syncthreads();
#pragma unroll
    for (int j = 0; j < 32; ++j) {
      vf2 a = *(const vf2*)&As[j * 36 + 2 * ti];  // rows 2ti, 2ti+1
      vf4 b4 = *(const vf4*)&Bs[j * 68 + td * 4];
#pragma unroll
      for (int c = 0; c < 4; ++c) {
        acc[0][c] += a[0] * b4[c];
        acc[1][c] += a[1] * b4[c];
      }
    }
  }
#pragma unroll
  for (int r = 0; r < 2; ++r) {
    vf4 o = {acc[r][0], acc[r][1], acc[r][2], acc[r][3]};
    *(vf4*)&out[(((b << 8) + i0 + 2 * ti + r) << 8) + d0 + td * 4] = o;
  }
}

// ---------------------------------------------------------------------------
extern "C" void kernel_launch(void* const* d_in, const int* in_sizes, int n_in,
                              void* d_out, int out_size, void* d_ws, size_t ws_size,
                              hipStream_t stream) {
  const float* queries = (const float*)d_in[0];
  const float* keyes = (const float*)d_in[1];
  const float* values = (const float*)d_in[2];
  const int* valid_lens = (const int*)d_in[3];
  const float* Wq = (const float*)d_in[4];
  const float* Wk = (const float*)d_in[5];
  const float* Wv = (const float*)d_in[6];
  float* out = (float*)d_out;

  float* QpH = (float*)d_ws;       // 4 x 2 MB (k-quarter exponentials)
  float* KpH = QpH + 4 * 524288;   // 4 x 2 MB
  float* E = KpH + 4 * 524288;     // 2 MB, [b][j][i]
  float* Rsum = E + 524288;        // 8 KB, [b][j]

  proj_kernel<<<dim3(32, 4, 4), 256, 0, stream>>>(queries, keyes, Wq, Wk,
                                                  QpH, KpH, Rsum);
  scores_exp_kernel<<<dim3(8, 8, 8), 256, 0, stream>>>(QpH, KpH, Wv,
                                                       valid_lens, E, Rsum);
  out_kernel<<<dim3(8, 4, 8), 256, 0, stream>>>(E, Rsum, values, out);
}

// Round 7
// 107.600 us; speedup vs baseline: 1.0190x; 1.0190x over previous
//
#include <hip/hip_runtime.h>

typedef float vf4 __attribute__((ext_vector_type(4)));
typedef float vf2 __attribute__((ext_vector_type(2)));

#define LOG2E 1.4426950408889634f
#define TWO_LOG2E 2.8853900817779268f

__device__ __forceinline__ float fexp2(float x) { return __builtin_amdgcn_exp2f(x); }
__device__ __forceinline__ float frcp(float x) { return __builtin_amdgcn_rcpf(x); }

// ---------------------------------------------------------------------------
// Kernel 1 v4: projections, FULL k=256 per block -> stores a SINGLE
// exponential Ep = exp2(2*log2e * acc) per element (QpH/KpH = 2 MB each,
// HALF of R5's k-split x2 volume; R6 showed intermediate volume is a
// first-class cost: x2 volume cost ~4-5 us).
// Geometry: 512 threads = 2 k-groups x 256; each group runs the R5-proven
// 64x64-tile 4x4-micro inner loop on its own LDS buffers for its k-half,
// then one cross-group LDS reduce + exp + store.  Grid 64x4 = 256 blocks
// = 1 block/CU, 8 waves/CU = 2/SIMD (R4 lesson: never below 2/SIMD).
// Block (0,0) also zeroes Rsum[2048] (512 thr x 4 floats).
__global__ __launch_bounds__(512) void proj_kernel(
    const float* __restrict__ queries, const float* __restrict__ keyes,
    const float* __restrict__ Wq, const float* __restrict__ Wk,
    float* __restrict__ QpH, float* __restrict__ KpH,
    float* __restrict__ Rsum) {
  // layout: At[g] = smem + g*1088, Bt[g] = smem + 2176 + g*1088 (16x68 each);
  // red = smem (4096 floats, reused after the final compute barrier).
  __shared__ alignas(16) float smem[4352];
  const int t = threadIdx.x;
  if (blockIdx.x == 0 && blockIdx.y == 0) {
    *(vf4*)&Rsum[t * 4] = (vf4){0.f, 0.f, 0.f, 0.f};
  }
  const int m0 = blockIdx.x * 64;
  const int n0 = blockIdx.y * 64;
  const bool isQ = (m0 < 2048);
  const float* X = isQ ? queries : keyes;
  const float* W = isQ ? Wq : Wk;
  float* C = isQ ? QpH : KpH;
  const int mb = isQ ? m0 : (m0 - 2048);

  const int g = t >> 8;    // k-half group (0: k 0..127, 1: k 128..255)
  const int tl = t & 255;  // lane within group
  float* At = smem + g * 1088;
  float* Bt = smem + 2176 + g * 1088;
  const int lm = tl >> 2;
  const int lq = tl & 3;
  const int mm4 = (tl & 15) * 4;
  const int nn4 = (tl >> 4) * 4;

  float acc[4][4] = {};
  const int kbase = g * 128;
  for (int kc = kbase; kc < kbase + 128; kc += 16) {
    __syncthreads();
    vf4 xa = *(const vf4*)&X[(mb + lm) * 256 + kc + lq * 4];
    vf4 wb = *(const vf4*)&W[(n0 + lm) * 256 + kc + lq * 4];
#pragma unroll
    for (int c = 0; c < 4; ++c) {
      At[(lq * 4 + c) * 68 + lm] = xa[c];
      Bt[(lq * 4 + c) * 68 + lm] = wb[c];
    }
    __syncthreads();
#pragma unroll
    for (int kk = 0; kk < 16; ++kk) {
      vf4 a4 = *(const vf4*)&At[kk * 68 + mm4];
      vf4 b4 = *(const vf4*)&Bt[kk * 68 + nn4];
#pragma unroll
      for (int i = 0; i < 4; ++i)
#pragma unroll
        for (int j = 0; j < 4; ++j) acc[i][j] += a4[i] * b4[j];
    }
  }
  __syncthreads();
  // cross-group combine: g1 dumps its partial acc; g0 adds, exps, stores.
  float* red = smem;  // 256 threads x 16 floats = 4096 <= 4352
  if (g == 1) {
#pragma unroll
    for (int i = 0; i < 4; ++i)
      *(vf4*)&red[tl * 16 + i * 4] =
          (vf4){acc[i][0], acc[i][1], acc[i][2], acc[i][3]};
  }
  __syncthreads();
  if (g == 0) {
#pragma unroll
    for (int i = 0; i < 4; ++i) {
      vf4 p = *(const vf4*)&red[tl * 16 + i * 4];
      vf4 o = {fexp2((acc[i][0] + p[0]) * TWO_LOG2E),
               fexp2((acc[i][1] + p[1]) * TWO_LOG2E),
               fexp2((acc[i][2] + p[2]) * TWO_LOG2E),
               fexp2((acc[i][3] + p[3]) * TWO_LOG2E)};
      *(vf4*)&C[(mb + mm4 + i) * 256 + n0 + nn4] = o;
    }
  }
}

// ---------------------------------------------------------------------------
// Kernel 2 (dominant): scores via precomputed exponentials.  R3/R5-proven
// structure; staging now reads a SINGLE full-exp stream per operand (was 2
// half-exp streams + product).  Wv through scalar cache, 4-way rational rcp
// combining.  score = Swv - 2*acc;  E[b][j][i] = masked ? 1 : exp(score);
// fused row sums via atomicAdd into Rsum.  Tile 32i x 32j x h=256,
// grid 8x8x8 = 512 (2 blocks/CU, 8 waves/CU).  XOR-swizzled LDS tiles.
__global__ __launch_bounds__(256) void scores_exp_kernel(
    const float* __restrict__ QpH, const float* __restrict__ KpH,
    const float* __restrict__ Wv, const int* __restrict__ valid_lens,
    float* __restrict__ E, float* __restrict__ Rsum) {
  __shared__ alignas(16) float Qs[32 * 32];
  __shared__ alignas(16) float Ks[32 * 32];
  const int t = threadIdx.x;
  const int i0 = blockIdx.x * 32;
  const int j0 = blockIdx.y * 32;
  const int b = blockIdx.z;
  const int ti = t & 15;   // i = i0 + ti (+16)
  const int tj = t >> 4;   // j = j0 + tj (+16)

  float Swv;  // sum_h wv[h]
  {
    vf4 w4 = *(const vf4*)&Wv[(t & 63) * 4];
    float sw = w4[0] + w4[1] + w4[2] + w4[3];
#pragma unroll
    for (int off = 1; off < 64; off <<= 1) sw += __shfl_xor(sw, off, 64);
    Swv = sw;
  }

  const int srow = t >> 3;       // staging row 0..31
  const int scg = t & 7;         // staging col-group 0..7
  const int swcol = ((scg ^ (srow & 7)) << 2);
  const int qxor = ti & 7;
  const int kxor = tj & 7;

  float acc[2][2] = {};
  for (int hc = 0; hc < 8; ++hc) {
    __syncthreads();
    const int qoff = (((b << 8) + i0 + srow) << 8) + hc * 32 + scg * 4;
    const int koff = (((b << 8) + j0 + srow) << 8) + hc * 32 + scg * 4;
    *(vf4*)&Qs[srow * 32 + swcol] = *(const vf4*)&QpH[qoff];
    *(vf4*)&Ks[srow * 32 + swcol] = *(const vf4*)&KpH[koff];
    __syncthreads();
#pragma unroll
    for (int hh = 0; hh < 8; ++hh) {
      vf4 q0 = *(const vf4*)&Qs[ti * 32 + ((hh ^ qxor) << 2)];
      vf4 q1 = *(const vf4*)&Qs[(ti + 16) * 32 + ((hh ^ qxor) << 2)];
      vf4 k0 = *(const vf4*)&Ks[tj * 32 + ((hh ^ kxor) << 2)];
      vf4 k1 = *(const vf4*)&Ks[(tj + 16) * 32 + ((hh ^ kxor) << 2)];
      const int hb = hc * 32 + hh * 4;
      const float w0 = Wv[hb + 0];  // uniform -> scalar cache, not LDS
      const float w1 = Wv[hb + 1];
      const float w2 = Wv[hb + 2];
      const float w3 = Wv[hb + 3];
      // sum_e w_e / A_e with one rcp: (n01*d23 + n23*d01) / (d01*d23)
      auto term = [&](const vf4& q, const vf4& k, float& a) {
        float A0 = __builtin_fmaf(q[0], k[0], 1.0f);
        float A1 = __builtin_fmaf(q[1], k[1], 1.0f);
        float A2 = __builtin_fmaf(q[2], k[2], 1.0f);
        float A3 = __builtin_fmaf(q[3], k[3], 1.0f);
        float d01 = A0 * A1;
        float d23 = A2 * A3;
        float n01 = __builtin_fmaf(w0, A1, w1 * A0);
        float n23 = __builtin_fmaf(w2, A3, w3 * A2);
        float num = __builtin_fmaf(n01, d23, n23 * d01);
        a = __builtin_fmaf(num, frcp(d01 * d23), a);
      };
      term(q0, k0, acc[0][0]);
      term(q0, k1, acc[0][1]);
      term(q1, k0, acc[1][0]);
      term(q1, k1, acc[1][1]);
    }
  }

  const int len = valid_lens[b];
#pragma unroll
  for (int c = 0; c < 2; ++c) {
    const int j = j0 + tj + 16 * c;
    const bool masked = (j >= len);
    float ev[2];
#pragma unroll
    for (int r = 0; r < 2; ++r) {
      const int i = i0 + ti + 16 * r;
      const float score = Swv - 2.0f * acc[r][c];
      ev[r] = masked ? 1.0f : fexp2(score * LOG2E);
      E[(((b << 8) + j) << 8) + i] = ev[r];
    }
    float s = ev[0] + ev[1];
#pragma unroll
    for (int off = 1; off < 16; off <<= 1) s += __shfl_xor(s, off, 64);
    if (ti == 0) atomicAdd(&Rsum[(b << 8) + j], s);
  }
}

// ---------------------------------------------------------------------------
// Kernel 3: out[b,i,d] = sum_j (E[b,j,i]/Rsum[b,j]) * V[b,j,d].
// R5-proven v2: i micro-tile {2ti, 2ti+1} -> single b64 A-read per j.
// Tile 32i x 64d, 256 threads, grid 8x4x8 = 256 blocks.
__global__ __launch_bounds__(256) void out_kernel(
    const float* __restrict__ E, const float* __restrict__ Rsum,
    const float* __restrict__ V, float* __restrict__ out) {
  __shared__ alignas(16) float As[32 * 36];  // [j][i]
  __shared__ alignas(16) float Bs[32 * 68];  // [j][d]
  const int t = threadIdx.x;
  const int i0 = blockIdx.x * 32;
  const int d0 = blockIdx.y * 64;
  const int b = blockIdx.z;
  const int ti = t & 15;   // i-pair: rows 2ti, 2ti+1
  const int td = t >> 4;   // d = d0 + td*4
  const int sr = t >> 3;   // staging row 0..31
  const int sc4 = (t & 7) * 4;

  float acc[2][4] = {};
  for (int jc = 0; jc < 8; ++jc) {
    const int jb = jc * 32;
    __syncthreads();
    const float rj = frcp(Rsum[(b << 8) + jb + sr]);
    {
      vf4 a = *(const vf4*)&E[(((b << 8) + jb + sr) << 8) + i0 + sc4];
      *(vf4*)&As[sr * 36 + sc4] = a * rj;
    }
#pragma unroll
    for (int s = 0; s < 2; ++s) {
      const int col = sc4 + s * 32;
      *(vf4*)&Bs[sr * 68 + col] =
          *(const vf4*)&V[(((b << 8) + jb + sr) << 8) + d0 + col];
    }
    __syncthreads();
#pragma unroll
    for (int j = 0; j < 32; ++j) {
      vf2 a = *(const vf2*)&As[j * 36 + 2 * ti];  // rows 2ti, 2ti+1
      vf4 b4 = *(const vf4*)&Bs[j * 68 + td * 4];
#pragma unroll
      for (int c = 0; c < 4; ++c) {
        acc[0][c] += a[0] * b4[c];
        acc[1][c] += a[1] * b4[c];
      }
    }
  }
#pragma unroll
  for (int r = 0; r < 2; ++r) {
    vf4 o = {acc[r][0], acc[r][1], acc[r][2], acc[r][3]};
    *(vf4*)&out[(((b << 8) + i0 + 2 * ti + r) << 8) + d0 + td * 4] = o;
  }
}

// ---------------------------------------------------------------------------
extern "C" void kernel_launch(void* const* d_in, const int* in_sizes, int n_in,
                              void* d_out, int out_size, void* d_ws, size_t ws_size,
                              hipStream_t stream) {
  const float* queries = (const float*)d_in[0];
  const float* keyes = (const float*)d_in[1];
  const float* values = (const float*)d_in[2];
  const int* valid_lens = (const int*)d_in[3];
  const float* Wq = (const float*)d_in[4];
  const float* Wk = (const float*)d_in[5];
  const float* Wv = (const float*)d_in[6];
  float* out = (float*)d_out;

  float* QpH = (float*)d_ws;       // 2 MB (full-k exponentials)
  float* KpH = QpH + 524288;       // 2 MB
  float* E = KpH + 524288;         // 2 MB, [b][j][i]
  float* Rsum = E + 524288;        // 8 KB, [b][j]

  proj_kernel<<<dim3(64, 4), 512, 0, stream>>>(queries, keyes, Wq, Wk,
                                               QpH, KpH, Rsum);
  scores_exp_kernel<<<dim3(8, 8, 8), 256, 0, stream>>>(QpH, KpH, Wv,
                                                       valid_lens, E, Rsum);
  out_kernel<<<dim3(8, 4, 8), 256, 0, stream>>>(E, Rsum, values, out);
}

// Round 8
// 107.038 us; speedup vs baseline: 1.0243x; 1.0053x over previous
//
#include <hip/hip_runtime.h>

typedef float vf4 __attribute__((ext_vector_type(4)));
typedef float vf2 __attribute__((ext_vector_type(2)));

#define LOG2E 1.4426950408889634f
#define TWO_LOG2E 2.8853900817779268f

__device__ __forceinline__ float fexp2(float x) { return __builtin_amdgcn_exp2f(x); }
__device__ __forceinline__ float frcp(float x) { return __builtin_amdgcn_rcpf(x); }

// ---------------------------------------------------------------------------
// Kernel 1: projections (R5-proven, frozen). k-split x2, grid (64,4,2)=512 =
// 2 blocks/CU, 8 waves/CU. exp folded into epilogue: stores
// Ep = exp2(2*log2e * acc_half); scores uses tanh(q+k) = 1 - 2/(Eq*Fk+1),
// Eq = Eq1*Eq2.  Block (0,0,0) zeroes Rsum[2048].
// R4/R6/R7 lessons: 1 wave/SIMD kills it; k-split x4 doubles intermediate
// volume (-); full-k at 1 block/CU exposes barriers (-). This config wins.
__global__ __launch_bounds__(256) void proj_kernel(
    const float* __restrict__ queries, const float* __restrict__ keyes,
    const float* __restrict__ Wq, const float* __restrict__ Wk,
    float* __restrict__ QpH, float* __restrict__ KpH,
    float* __restrict__ Rsum) {
  __shared__ alignas(16) float At[16 * 68];  // [k][m]
  __shared__ alignas(16) float Bt[16 * 68];  // [k][n]
  const int t = threadIdx.x;
  if (blockIdx.x == 0 && blockIdx.y == 0 && blockIdx.z == 0) {
    *(vf4*)&Rsum[t * 8] = (vf4){0.f, 0.f, 0.f, 0.f};
    *(vf4*)&Rsum[t * 8 + 4] = (vf4){0.f, 0.f, 0.f, 0.f};
  }
  const int m0 = blockIdx.x * 64;
  const int n0 = blockIdx.y * 64;
  const int k0 = blockIdx.z * 128;  // k-half
  const bool isQ = (m0 < 2048);
  const float* X = isQ ? queries : keyes;
  const float* W = isQ ? Wq : Wk;
  float* C = (isQ ? QpH : KpH) + blockIdx.z * 524288;
  const int mb = isQ ? m0 : (m0 - 2048);

  const int lm = t >> 2;
  const int lq = t & 3;
  const int mm4 = (t & 15) * 4;
  const int nn4 = (t >> 4) * 4;

  float acc[4][4] = {};
  for (int kc = k0; kc < k0 + 128; kc += 16) {
    __syncthreads();
    vf4 xa = *(const vf4*)&X[(mb + lm) * 256 + kc + lq * 4];
    vf4 wb = *(const vf4*)&W[(n0 + lm) * 256 + kc + lq * 4];
#pragma unroll
    for (int c = 0; c < 4; ++c) {
      At[(lq * 4 + c) * 68 + lm] = xa[c];
      Bt[(lq * 4 + c) * 68 + lm] = wb[c];
    }
    __syncthreads();
#pragma unroll
    for (int kk = 0; kk < 16; ++kk) {
      vf4 a4 = *(const vf4*)&At[kk * 68 + mm4];
      vf4 b4 = *(const vf4*)&Bt[kk * 68 + nn4];
#pragma unroll
      for (int i = 0; i < 4; ++i)
#pragma unroll
        for (int j = 0; j < 4; ++j) acc[i][j] += a4[i] * b4[j];
    }
  }
#pragma unroll
  for (int i = 0; i < 4; ++i) {
    vf4 o = {fexp2(acc[i][0] * TWO_LOG2E), fexp2(acc[i][1] * TWO_LOG2E),
             fexp2(acc[i][2] * TWO_LOG2E), fexp2(acc[i][3] * TWO_LOG2E)};
    *(vf4*)&C[(mb + mm4 + i) * 256 + n0 + nn4] = o;
  }
}

// ---------------------------------------------------------------------------
// Kernel 2 (dominant) v3: scores via precomputed exponentials.
// Changes vs R5-proven version:
//  - FULL-TILE staging: both 32x256 operand tiles staged once (64 KB LDS,
//    2 blocks/CU = 128 <= 160 KB), ONE barrier, then a 64-step barrier-free
//    compute loop.  Removes 16 barriers and batches all 32 staging loads
//    into a single latency exposure.
//  - 8-way rational combining: one v_rcp per 8 h-terms (pair hh, hh+1).
//    Range: A <= ~3e4, 8-product <= ~1e36 < fp32 max; h-independence makes
//    the joint tail negligible; den normal -> frcp exact-safe.
// Wv via scalar cache.  score = Swv - 2*acc;  E[b][j][i] = masked ? 1 :
// exp(score); fused row sums via atomicAdd into Rsum.
// Tile 32i x 32j x h=256, grid 8x8x8 = 512 (2 blocks/CU, 8 waves/CU).
// Per-chunk XOR-swizzled LDS layout identical to the proven version.
__global__ __launch_bounds__(256, 2) void scores_exp_kernel(
    const float* __restrict__ QpH, const float* __restrict__ KpH,
    const float* __restrict__ Wv, const int* __restrict__ valid_lens,
    float* __restrict__ E, float* __restrict__ Rsum) {
  __shared__ alignas(16) float Qs[8 * 32 * 32];  // [hc][row][32], swizzled
  __shared__ alignas(16) float Ks[8 * 32 * 32];
  const int t = threadIdx.x;
  const int i0 = blockIdx.x * 32;
  const int j0 = blockIdx.y * 32;
  const int b = blockIdx.z;
  const int ti = t & 15;   // i = i0 + ti (+16)
  const int tj = t >> 4;   // j = j0 + tj (+16)

  float Swv;  // sum_h wv[h]
  {
    vf4 w4 = *(const vf4*)&Wv[(t & 63) * 4];
    float sw = w4[0] + w4[1] + w4[2] + w4[3];
#pragma unroll
    for (int off = 1; off < 64; off <<= 1) sw += __shfl_xor(sw, off, 64);
    Swv = sw;
  }

  const int srow = t >> 3;       // staging row 0..31
  const int scg = t & 7;         // staging col-group 0..7
  const int swcol = ((scg ^ (srow & 7)) << 2);
  const int qxor = ti & 7;
  const int kxor = tj & 7;

  // ---- stage ALL 8 hc-chunks, then one barrier ----
#pragma unroll
  for (int hc = 0; hc < 8; ++hc) {
    const int qoff = (((b << 8) + i0 + srow) << 8) + hc * 32 + scg * 4;
    const int koff = (((b << 8) + j0 + srow) << 8) + hc * 32 + scg * 4;
    vf4 qv = *(const vf4*)&QpH[qoff] * *(const vf4*)&QpH[524288 + qoff];
    vf4 kv = *(const vf4*)&KpH[koff] * *(const vf4*)&KpH[524288 + koff];
    *(vf4*)&Qs[hc * 1024 + srow * 32 + swcol] = qv;  // product of half-exps
    *(vf4*)&Ks[hc * 1024 + srow * 32 + swcol] = kv;
  }
  __syncthreads();

  float acc[2][2] = {};
#pragma unroll 2
  for (int hc = 0; hc < 8; ++hc) {
    const float* Qc = &Qs[hc * 1024];
    const float* Kc = &Ks[hc * 1024];
#pragma unroll
    for (int hh = 0; hh < 8; hh += 2) {
      vf4 q0a = *(const vf4*)&Qc[ti * 32 + ((hh ^ qxor) << 2)];
      vf4 q1a = *(const vf4*)&Qc[(ti + 16) * 32 + ((hh ^ qxor) << 2)];
      vf4 k0a = *(const vf4*)&Kc[tj * 32 + ((hh ^ kxor) << 2)];
      vf4 k1a = *(const vf4*)&Kc[(tj + 16) * 32 + ((hh ^ kxor) << 2)];
      vf4 q0b = *(const vf4*)&Qc[ti * 32 + (((hh + 1) ^ qxor) << 2)];
      vf4 q1b = *(const vf4*)&Qc[(ti + 16) * 32 + (((hh + 1) ^ qxor) << 2)];
      vf4 k0b = *(const vf4*)&Kc[tj * 32 + (((hh + 1) ^ kxor) << 2)];
      vf4 k1b = *(const vf4*)&Kc[(tj + 16) * 32 + (((hh + 1) ^ kxor) << 2)];
      const int hb = hc * 32 + hh * 4;
      const float w0 = Wv[hb + 0];  // uniform -> scalar cache
      const float w1 = Wv[hb + 1];
      const float w2 = Wv[hb + 2];
      const float w3 = Wv[hb + 3];
      const float w4 = Wv[hb + 4];
      const float w5 = Wv[hb + 5];
      const float w6 = Wv[hb + 6];
      const float w7 = Wv[hb + 7];
      // sum over 8 h of w_e/A_e with ONE rcp
      auto term8 = [&](const vf4& qa, const vf4& ka, const vf4& qb,
                       const vf4& kb, float& a) {
        float A0 = __builtin_fmaf(qa[0], ka[0], 1.0f);
        float A1 = __builtin_fmaf(qa[1], ka[1], 1.0f);
        float A2 = __builtin_fmaf(qa[2], ka[2], 1.0f);
        float A3 = __builtin_fmaf(qa[3], ka[3], 1.0f);
        float A4 = __builtin_fmaf(qb[0], kb[0], 1.0f);
        float A5 = __builtin_fmaf(qb[1], kb[1], 1.0f);
        float A6 = __builtin_fmaf(qb[2], kb[2], 1.0f);
        float A7 = __builtin_fmaf(qb[3], kb[3], 1.0f);
        float d01 = A0 * A1, d23 = A2 * A3, d45 = A4 * A5, d67 = A6 * A7;
        float n01 = __builtin_fmaf(w0, A1, w1 * A0);
        float n23 = __builtin_fmaf(w2, A3, w3 * A2);
        float n45 = __builtin_fmaf(w4, A5, w5 * A4);
        float n67 = __builtin_fmaf(w6, A7, w7 * A6);
        float da = d01 * d23, db = d45 * d67;
        float na = __builtin_fmaf(n01, d23, n23 * d01);
        float nb = __builtin_fmaf(n45, d67, n67 * d45);
        float num = __builtin_fmaf(na, db, nb * da);
        a = __builtin_fmaf(num, frcp(da * db), a);
      };
      term8(q0a, k0a, q0b, k0b, acc[0][0]);
      term8(q0a, k1a, q0b, k1b, acc[0][1]);
      term8(q1a, k0a, q1b, k0b, acc[1][0]);
      term8(q1a, k1a, q1b, k1b, acc[1][1]);
    }
  }

  const int len = valid_lens[b];
#pragma unroll
  for (int c = 0; c < 2; ++c) {
    const int j = j0 + tj + 16 * c;
    const bool masked = (j >= len);
    float ev[2];
#pragma unroll
    for (int r = 0; r < 2; ++r) {
      const int i = i0 + ti + 16 * r;
      const float score = Swv - 2.0f * acc[r][c];
      ev[r] = masked ? 1.0f : fexp2(score * LOG2E);
      E[(((b << 8) + j) << 8) + i] = ev[r];
    }
    float s = ev[0] + ev[1];
#pragma unroll
    for (int off = 1; off < 16; off <<= 1) s += __shfl_xor(s, off, 64);
    if (ti == 0) atomicAdd(&Rsum[(b << 8) + j], s);
  }
}

// ---------------------------------------------------------------------------
// Kernel 3: out[b,i,d] = sum_j (E[b,j,i]/Rsum[b,j]) * V[b,j,d].
// R5-proven v2 (frozen): i micro-tile {2ti, 2ti+1} -> single b64 A-read per j.
// Tile 32i x 64d, 256 threads, grid 8x4x8 = 256 blocks.
__global__ __launch_bounds__(256) void out_kernel(
    const float* __restrict__ E, const float* __restrict__ Rsum,
    const float* __restrict__ V, float* __restrict__ out) {
  __shared__ alignas(16) float As[32 * 36];  // [j][i]
  __shared__ alignas(16) float Bs[32 * 68];  // [j][d]
  const int t = threadIdx.x;
  const int i0 = blockIdx.x * 32;
  const int d0 = blockIdx.y * 64;
  const int b = blockIdx.z;
  const int ti = t & 15;   // i-pair: rows 2ti, 2ti+1
  const int td = t >> 4;   // d = d0 + td*4
  const int sr = t >> 3;   // staging row 0..31
  const int sc4 = (t & 7) * 4;

  float acc[2][4] = {};
  for (int jc = 0; jc < 8; ++jc) {
    const int jb = jc * 32;
    __syncthreads();
    const float rj = frcp(Rsum[(b << 8) + jb + sr]);
    {
      vf4 a = *(const vf4*)&E[(((b << 8) + jb + sr) << 8) + i0 + sc4];
      *(vf4*)&As[sr * 36 + sc4] = a * rj;
    }
#pragma unroll
    for (int s = 0; s < 2; ++s) {
      const int col = sc4 + s * 32;
      *(vf4*)&Bs[sr * 68 + col] =
          *(const vf4*)&V[(((b << 8) + jb + sr) << 8) + d0 + col];
    }
    __syncthreads();
#pragma unroll
    for (int j = 0; j < 32; ++j) {
      vf2 a = *(const vf2*)&As[j * 36 + 2 * ti];  // rows 2ti, 2ti+1
      vf4 b4 = *(const vf4*)&Bs[j * 68 + td * 4];
#pragma unroll
      for (int c = 0; c < 4; ++c) {
        acc[0][c] += a[0] * b4[c];
        acc[1][c] += a[1] * b4[c];
      }
    }
  }
#pragma unroll
  for (int r = 0; r < 2; ++r) {
    vf4 o = {acc[r][0], acc[r][1], acc[r][2], acc[r][3]};
    *(vf4*)&out[(((b << 8) + i0 + 2 * ti + r) << 8) + d0 + td * 4] = o;
  }
}

// ---------------------------------------------------------------------------
extern "C" void kernel_launch(void* const* d_in, const int* in_sizes, int n_in,
                              void* d_out, int out_size, void* d_ws, size_t ws_size,
                              hipStream_t stream) {
  const float* queries = (const float*)d_in[0];
  const float* keyes = (const float*)d_in[1];
  const float* values = (const float*)d_in[2];
  const int* valid_lens = (const int*)d_in[3];
  const float* Wq = (const float*)d_in[4];
  const float* Wk = (const float*)d_in[5];
  const float* Wv = (const float*)d_in[6];
  float* out = (float*)d_out;

  float* QpH = (float*)d_ws;       // 2 x 2 MB (k-half exponentials)
  float* KpH = QpH + 2 * 524288;   // 2 x 2 MB
  float* E = KpH + 2 * 524288;     // 2 MB, [b][j][i]
  float* Rsum = E + 524288;        // 8 KB, [b][j]

  proj_kernel<<<dim3(64, 4, 2), 256, 0, stream>>>(queries, keyes, Wq, Wk,
                                                  QpH, KpH, Rsum);
  scores_exp_kernel<<<dim3(8, 8, 8), 256, 0, stream>>>(QpH, KpH, Wv,
                                                       valid_lens, E, Rsum);
  out_kernel<<<dim3(8, 4, 8), 256, 0, stream>>>(E, Rsum, values, out);
}